// Round 5
// baseline (1549.644 us; speedup 1.0000x reference)
//
#include <hip/hip_runtime.h>
#include <hip/hip_fp16.h>
#include <hip/hip_cooperative_groups.h>

namespace cg = cooperative_groups;

// H2GCNConv: out[:, 0:128]  = segment_sum(vals1[e] * x[col1[e]], row1)
//            out[:, 128:256] = segment_sum(vals2[e] * x[col2[e]], row2)
// N=50000 (fits 16 bits), D=128, fp32 in/out.
// Round 5: ONE cooperative kernel. Phases:
//  P0 zero meta + cvt x->bf16 | P1 row-hist + (bucket,shard)-hist
//  P2 scans (block sums -> top scan -> apply) | P3 sharded bucket scatter
//  P4 per-bucket CSR build (LDS cursors)     | P5 per-row-wave gather.
// shard = blockIdx&7 (~XCD): consecutive appends in a segment come from one
// XCD's L2 -> full-line writebacks, kills round-4's 8x write amplification.

constexpr int D = 128;
constexpr int OUT_STRIDE = 256;
constexpr int GRID_BLOCKS = 1024;   // 4 blocks/CU x 256 CUs -> coop-safe
constexpr int BLOCK = 256;
constexpr int BSHIFT = 6;           // 64 rows per bucket

struct KP {
  const float* x;
  const int* row1; const int* col1; const float* vals1;
  const int* row2; const int* col2; const float* vals2;
  float* out;
  int n, e1, e2, nx4, nbuk, zn;
  int* rs1; int* rs2;          // n+1 row starts per hop (counts -> scan)
  int* ss;                     // 2*nbuk*8+1 (bucket,shard) starts (+sentinel)
  int* scur;                   // 2*nbuk*8 segment cursors
  int* csums;                  // 576 scan block sums
  int* zbase;                  // start of contiguous zero region
  unsigned short* xb;          // bf16 x
  unsigned* tmp_rc;            // pass-1: row | col<<16
  unsigned short* tmp_v;       // pass-1: val fp16
  unsigned* csr;               // pass-2: col | fp16val<<16
};

__device__ __forceinline__ unsigned short f2b(float f) {
  unsigned u = __float_as_uint(f);
  u += 0x7fffu + ((u >> 16) & 1u);
  return (unsigned short)(u >> 16);
}
__device__ __forceinline__ float blo(unsigned u) { return __uint_as_float(u << 16); }
__device__ __forceinline__ float bhi(unsigned u) { return __uint_as_float(u & 0xffff0000u); }
__device__ __forceinline__ float h2f(unsigned q) {
  return __half2float(__ushort_as_half((unsigned short)(q >> 16)));
}

__launch_bounds__(BLOCK, 4)
__global__ void fused_kernel(KP p) {
  cg::grid_group grid = cg::this_grid();
  __shared__ int w4[4];
  __shared__ int lcur[64];

  const int GT   = GRID_BLOCKS * BLOCK;
  const int g0   = blockIdx.x * BLOCK + threadIdx.x;
  const int etot = p.e1 + p.e2;
  const int lane = threadIdx.x & 63;
  const int myshard = blockIdx.x & 7;

  // ---------------- P0: zero metadata, cvt x -> bf16 ----------------
  for (int i = g0; i < p.zn; i += GT) p.zbase[i] = 0;
  for (int i = g0; i < p.nx4; i += GT) {
    const float4 v = ((const float4*)p.x)[i];
    ushort4 o; o.x = f2b(v.x); o.y = f2b(v.y); o.z = f2b(v.z); o.w = f2b(v.w);
    ((ushort4*)p.xb)[i] = o;
  }
  grid.sync();

  // ---------------- P1: row hist + (bucket,shard) hist ----------------
  for (int i = g0; i < etot; i += GT) {
    const int hop = (i >= p.e1);
    const int j = hop ? i - p.e1 : i;
    const int r = hop ? p.row2[j] : p.row1[j];
    atomicAdd((hop ? p.rs2 : p.rs1) + r, 1);
    atomicAdd(p.ss + ((((hop ? p.nbuk : 0) + (r >> BSHIFT)) << 3) + myshard), 1);
  }
  grid.sync();

  // ---------------- P2A: per-block chunk sums ----------------
  int* arr = nullptr; int alen = 0, lb = 0, coff = 0, nbk = 0;
  if (blockIdx.x < 256)      { arr = p.rs1; alen = p.n + 1;          lb = blockIdx.x;       coff = 0;   nbk = 256; }
  else if (blockIdx.x < 512) { arr = p.rs2; alen = p.n + 1;          lb = blockIdx.x - 256; coff = 256; nbk = 256; }
  else if (blockIdx.x < 576) { arr = p.ss;  alen = 2*p.nbuk*8 + 1;   lb = blockIdx.x - 512; coff = 512; nbk = 64;  }
  int myv = 0, myex = 0, mycpb = 0, mybase = 0;
  if (arr) {
    mycpb = (alen + nbk - 1) / nbk;          // 196 for all three jobs
    mybase = lb * mycpb;
    const int idx = mybase + threadIdx.x;
    myv = (threadIdx.x < mycpb && idx < alen) ? arr[idx] : 0;
    // block exclusive scan over thread order
    int acc = myv;
    #pragma unroll
    for (int d = 1; d < 64; d <<= 1) { int t = __shfl_up(acc, d); if (lane >= d) acc += t; }
    const int wid = threadIdx.x >> 6;
    if (lane == 63) w4[wid] = acc;
    __syncthreads();
    if (threadIdx.x == 0) { int s = 0; for (int k = 0; k < 4; ++k) { int t = w4[k]; w4[k] = s; s += t; } }
    __syncthreads();
    myex = acc - myv + w4[wid];
    if (threadIdx.x == 255) p.csums[coff + lb] = myex + myv;   // block total
  }
  grid.sync();

  // ---------------- P2B: block 0 scans the 3 csums segments ----------------
  if (blockIdx.x == 0) {
    const int wid = threadIdx.x >> 6;
    if (wid < 3) {
      const int off = wid * 256;
      const int len = (wid == 2) ? 64 : 256;
      const int per = len >> 6;               // 4,4,1
      int v[4]; int s = 0;
      for (int k = 0; k < per; ++k) { v[k] = p.csums[off + lane * per + k]; s += v[k]; }
      int ex = s;
      #pragma unroll
      for (int d = 1; d < 64; d <<= 1) { int t = __shfl_up(ex, d); if (lane >= d) ex += t; }
      ex -= s;
      int run = ex;
      for (int k = 0; k < per; ++k) { int t = v[k]; p.csums[off + lane * per + k] = run; run += t; }
    }
  }
  grid.sync();

  // ---------------- P2C: apply offsets -> exclusive starts in place ----------------
  if (arr) {
    const int idx = mybase + threadIdx.x;
    if (threadIdx.x < mycpb && idx < alen) arr[idx] = p.csums[coff + lb] + myex;
  }
  grid.sync();

  // ---------------- P3: sharded bucket scatter ----------------
  for (int i = g0; i < etot; i += GT) {
    const int hop = (i >= p.e1);
    const int j = hop ? i - p.e1 : i;
    const int r = hop ? p.row2[j] : p.row1[j];
    const int c = hop ? p.col2[j] : p.col1[j];
    const float v = hop ? p.vals2[j] : p.vals1[j];
    const int idx = (((hop ? p.nbuk : 0) + (r >> BSHIFT)) << 3) + myshard;
    const int pos = p.ss[idx] + atomicAdd(&p.scur[idx], 1);
    p.tmp_rc[pos] = (unsigned)r | ((unsigned)c << 16);
    p.tmp_v[pos]  = __half_as_ushort(__float2half(v));
  }
  grid.sync();

  // ---------------- P4: per-bucket CSR build (one block per bucket) ----------------
  for (int b = blockIdx.x; b < 2 * p.nbuk; b += GRID_BLOCKS) {
    const int hop = (b >= p.nbuk);
    const int* rs = hop ? p.rs2 : p.rs1;
    const unsigned cbase = hop ? (unsigned)p.e1 : 0u;
    const int s0 = p.ss[b << 3];
    const int s1 = p.ss[(b << 3) + 8];        // shards contiguous in scan order
    if (threadIdx.x < 64) lcur[threadIdx.x] = 0;
    __syncthreads();
    for (int t = s0 + (int)threadIdx.x; t < s1; t += BLOCK) {
      const unsigned e = p.tmp_rc[t];
      const int r = (int)(e & 0xffffu);
      const unsigned c = e >> 16;
      const unsigned hv = p.tmp_v[t];
      const int pos = rs[r] + atomicAdd(&lcur[r & 63], 1);
      p.csr[cbase + pos] = c | (hv << 16);
    }
    __syncthreads();
  }
  grid.sync();

  // ---------------- P5: gather, one wave per (row, hop) ----------------
  const int gw = g0 >> 6;
  const int GW = GT >> 6;
  const unsigned* xw = (const unsigned*)p.xb;
  for (int task = gw; task < 2 * p.n; task += GW) {
    const int hop = (task >= p.n);
    const int r = hop ? task - p.n : task;
    const int* rs = hop ? p.rs2 : p.rs1;
    const unsigned* cs = p.csr + (hop ? p.e1 : 0);
    int j = rs[r];
    const int end = rs[r + 1];
    float ax = 0.f, ay = 0.f;
    for (; j + 3 < end; j += 4) {
      const unsigned q0 = cs[j], q1 = cs[j + 1], q2 = cs[j + 2], q3 = cs[j + 3];
      const unsigned u0 = xw[(q0 & 0xffffu) * 64 + lane];
      const unsigned u1 = xw[(q1 & 0xffffu) * 64 + lane];
      const unsigned u2 = xw[(q2 & 0xffffu) * 64 + lane];
      const unsigned u3 = xw[(q3 & 0xffffu) * 64 + lane];
      const float v0 = h2f(q0), v1 = h2f(q1), v2 = h2f(q2), v3 = h2f(q3);
      ax += v0 * blo(u0); ay += v0 * bhi(u0);
      ax += v1 * blo(u1); ay += v1 * bhi(u1);
      ax += v2 * blo(u2); ay += v2 * bhi(u2);
      ax += v3 * blo(u3); ay += v3 * bhi(u3);
    }
    for (; j < end; ++j) {
      const unsigned q = cs[j];
      const unsigned u = xw[(q & 0xffffu) * 64 + lane];
      const float v = h2f(q);
      ax += v * blo(u); ay += v * bhi(u);
    }
    ((float2*)(p.out + (size_t)r * OUT_STRIDE + (hop ? D : 0)))[lane] = make_float2(ax, ay);
  }
}

extern "C" void kernel_launch(void* const* d_in, const int* in_sizes, int n_in,
                              void* d_out, int out_size, void* d_ws, size_t ws_size,
                              hipStream_t stream) {
  KP p;
  p.x     = (const float*)d_in[0];
  p.row1  = (const int*)  d_in[1];
  p.col1  = (const int*)  d_in[2];
  p.vals1 = (const float*)d_in[3];
  p.row2  = (const int*)  d_in[4];
  p.col2  = (const int*)  d_in[5];
  p.vals2 = (const float*)d_in[6];
  p.out   = (float*)d_out;

  p.e1   = in_sizes[1];
  p.e2   = in_sizes[4];
  p.n    = out_size / OUT_STRIDE;       // 50000 (< 65536: 16-bit packing ok)
  p.nx4  = in_sizes[0] / 4;
  p.nbuk = (p.n + 63) >> BSHIFT;        // 782
  const int etot = p.e1 + p.e2;
  const int NS = p.n + 1;
  const int NSS = 2 * p.nbuk * 8 + 1;   // 12513

  // ---- workspace layout (ints first, contiguous zero region) ----
  char* w = (char*)d_ws;
  size_t off = 0;
  p.zbase = (int*)w;
  p.rs1   = (int*)(w + off); off += (size_t)NS * 4;
  p.rs2   = (int*)(w + off); off += (size_t)NS * 4;
  p.ss    = (int*)(w + off); off += (size_t)NSS * 4;
  p.scur  = (int*)(w + off); off += (size_t)(NSS - 1) * 4;
  p.csums = (int*)(w + off); off += 576 * 4;
  p.zn    = (int)(off / 4);
  off = (off + 15) & ~(size_t)15;
  p.xb     = (unsigned short*)(w + off); off += (size_t)in_sizes[0] * 2;
  off = (off + 15) & ~(size_t)15;
  p.tmp_rc = (unsigned*)(w + off);       off += (size_t)etot * 4;
  off = (off + 15) & ~(size_t)15;
  p.tmp_v  = (unsigned short*)(w + off); off += (size_t)etot * 2;
  off = (off + 15) & ~(size_t)15;
  p.csr    = (unsigned*)(w + off);       off += (size_t)etot * 4;
  if (ws_size < off || p.n > 65535) return;   // loud failure rather than corruption

  void* args[] = { (void*)&p };
  hipLaunchCooperativeKernel((const void*)fused_kernel,
                             dim3(GRID_BLOCKS), dim3(BLOCK), args, 0, stream);
}